// Round 10
// baseline (377.962 us; speedup 1.0000x reference)
//
#include <hip/hip_runtime.h>

#define D 128
#define TD 384  // 3*D

// -------- K_prep: p[t] = sum_i v[i] * A[i*384 + t]  (ps|pd|pr concatenated) ----
__global__ void k_prep(const float* __restrict__ A, const float* __restrict__ v,
                       float* __restrict__ p) {
  __shared__ float vs[D];
  int t = threadIdx.x;
  if (t < D) vs[t] = v[t];
  __syncthreads();
  float acc = 0.f;
#pragma unroll 8
  for (int i = 0; i < D; ++i) acc += vs[i] * A[i * TD + t];
  p[t] = acc;
}

// -------- K_sl: sl = h @ loop_weight. k-split GEMV: block 256 = (half,j).
// Thread holds W[half*64 .. half*64+63][j] in 64 VGPRs (below the 128-VGPR
// occupancy cliff, so the allocator actually keeps them -- rounds 3/4 showed
// 128 pinned floats get spilled/remat'd, costing 82us of cache re-reads).
// h rows come in via wave-uniform s_load -> SGPR operand feeds v_fmac
// directly, zero per-FMA vector traffic. Halves combine via 2KB LDS.
__global__ __launch_bounds__(256) void k_sl(const float* __restrict__ h,
                                            const float* __restrict__ lw,
                                            float* __restrict__ sl, int N) {
  int t = threadIdx.x;
  int j = t & 127;
  int half = t >> 7;  // 0 or 1: k-range [half*64, half*64+64)
  float w[64];
#pragma unroll
  for (int kk = 0; kk < 64; ++kk)
    w[kk] = lw[(size_t)(half * 64 + kk) * D + j];
  __shared__ float red[4][D];
  int stride4 = gridDim.x * 4;
  for (int base = blockIdx.x * 4; base < N; base += stride4) {
    float acc[4] = {0.f, 0.f, 0.f, 0.f};
#pragma unroll
    for (int u = 0; u < 4; ++u) {
      int n = base + u;
      if (n < N) {
        const float* __restrict__ hr = h + (size_t)n * D + half * 64;  // uniform
        float a = 0.f;
#pragma unroll
        for (int kk = 0; kk < 64; ++kk) a = fmaf(hr[kk], w[kk], a);
        acc[u] = a;
      }
    }
    __syncthreads();  // LDS free from previous phase
    if (half == 1) {
#pragma unroll
      for (int u = 0; u < 4; ++u) red[u][j] = acc[u];
    }
    __syncthreads();
    if (half == 0) {
#pragma unroll
      for (int u = 0; u < 4; ++u) {
        int n = base + u;
        if (n < N) sl[(size_t)n * D + j] = acc[u] + red[u][j];
      }
    }
  }
}

// -------- K_scores + histogram (fused): wave-per-node dot products; extra blocks
// do the dst histogram for the CSR build. ------------------------------------
__global__ void k_scores_hist(const float* __restrict__ h, const float* __restrict__ emb,
                              const float* __restrict__ p, const int* __restrict__ dst,
                              float* __restrict__ ss, float* __restrict__ sd,
                              float* __restrict__ sr, int* __restrict__ cnt,
                              int N, int R, int E, int nbScore) {
  int t = threadIdx.x;
  if ((int)blockIdx.x < nbScore) {
    __shared__ float pl[TD];
    pl[t] = p[t];
    if (t < TD - 256) pl[256 + t] = p[256 + t];
    __syncthreads();
    int w = blockIdx.x * 4 + (t >> 6);
    int l = t & 63;
    if (w < N) {
      float x0 = h[(size_t)w * D + l];
      float x1 = h[(size_t)w * D + 64 + l];
      float a = x0 * pl[l] + x1 * pl[64 + l];
      float b = x0 * pl[128 + l] + x1 * pl[192 + l];
#pragma unroll
      for (int o = 32; o; o >>= 1) { a += __shfl_xor(a, o); b += __shfl_xor(b, o); }
      if (l == 0) { ss[w] = a; sd[w] = b; }
    } else if (w < N + R) {
      int r = w - N;
      float x0 = emb[(size_t)r * D + l];
      float x1 = emb[(size_t)r * D + 64 + l];
      float c = x0 * pl[256 + l] + x1 * pl[320 + l];
#pragma unroll
      for (int o = 32; o; o >>= 1) c += __shfl_xor(c, o);
      if (l == 0) sr[r] = c;
    }
  } else {
    int i = (blockIdx.x - nbScore) * 256 + t;
    int stride = (gridDim.x - nbScore) * 256;
    for (; i < E; i += stride) atomicAdd(&cnt[dst[i]], 1);
  }
}

// -------- 3-phase exclusive scan of cnt[0..N-1] ------------------------------
__global__ void k_scan1(int* __restrict__ cnt, int* __restrict__ bsum, int N) {
  __shared__ int wsum[16];
  int t = threadIdx.x, lane = t & 63, wid = t >> 6;
  int i = blockIdx.x * 1024 + t;
  int v = (i < N) ? cnt[i] : 0;
  int x = v;
#pragma unroll
  for (int o = 1; o < 64; o <<= 1) {
    int y = __shfl_up(x, o);
    if (lane >= o) x += y;
  }
  if (lane == 63) wsum[wid] = x;
  __syncthreads();
  if (t < 16) {
    int y = wsum[t];
#pragma unroll
    for (int o = 1; o < 16; o <<= 1) {
      int z = __shfl_up(y, o);
      if (t >= o) y += z;
    }
    wsum[t] = y;
  }
  __syncthreads();
  int woff = wid ? wsum[wid - 1] : 0;
  if (i < N) cnt[i] = woff + x - v;     // block-local exclusive scan
  if (t == 0) bsum[blockIdx.x] = wsum[15];
}

__global__ void k_scan2(int* __restrict__ bsum, int nsb) {
  int l = threadIdx.x;
  int v = (l < nsb) ? bsum[l] : 0;
  int x = v;
#pragma unroll
  for (int o = 1; o < 64; o <<= 1) {
    int y = __shfl_up(x, o);
    if (l >= o) x += y;
  }
  if (l < nsb) bsum[l] = x - v;          // exclusive block offsets, in place
}

__global__ void k_scan3(const int* __restrict__ bsum, int* __restrict__ cnt,
                        int* __restrict__ cur, int N, int E) {
  int i = blockIdx.x * 1024 + threadIdx.x;
  if (i < N) {
    int v = cnt[i] + bsum[blockIdx.x];
    cnt[i] = v;
    cur[i] = v;
  }
  if (i == 0) cnt[N] = E;
}

// -------- K_edge: per-edge logit + scatter into dst-sorted order --------------
__global__ void k_edge(const int* __restrict__ src, const int* __restrict__ dst,
                       const int* __restrict__ et, const float* __restrict__ ss,
                       const float* __restrict__ sd, const float* __restrict__ sr,
                       int* __restrict__ cur, float* __restrict__ esort,
                       int* __restrict__ ssort, int E) {
  int i = blockIdx.x * blockDim.x + threadIdx.x;
  if (i >= E) return;
  int s = src[i], d = dst[i], r = et[i];
  float e = ss[s] + sd[d] + sr[r];
  e = (e > 0.f) ? e : 0.01f * e;
  int pos = atomicAdd(&cur[d], 1);
  esort[pos] = e;
  ssort[pos] = s;
}

// -------- K_agg: one 256-thread block per dst node; fuses the final
// out = agg + sl add (sl = h@W selfloop, computed earlier by k_sl). ----------
__global__ __launch_bounds__(256) void k_agg(const float* __restrict__ h,
                                             const int* __restrict__ off,
                                             const float* __restrict__ esort,
                                             const int* __restrict__ ssort,
                                             const float* __restrict__ sl,
                                             float* __restrict__ out, int N) {
  int n = blockIdx.x;
  int t = threadIdx.x;
  int start = off[n], deg = off[n + 1] - start;
  int qc = t & 31;        // column quad
  int slot = t >> 5;      // edge slot 0..7
  if (deg == 0) {         // DGL keeps h unchanged; plus selfloop term
    if (slot == 0) {
      float4 hv = ((const float4*)(h + (size_t)n * D))[qc];
      float4 sv = ((const float4*)(sl + (size_t)n * D))[qc];
      hv.x += sv.x; hv.y += sv.y; hv.z += sv.z; hv.w += sv.w;
      ((float4*)(out + (size_t)n * D))[qc] = hv;
    }
    return;
  }
  __shared__ float4 part[8][32];
  __shared__ float dpart[8];
  __shared__ float mred[4];

  // pass A: segment max (all 256 threads)
  float m = -3.4e38f;
  for (int i = t; i < deg; i += 256) m = fmaxf(m, esort[start + i]);
#pragma unroll
  for (int o = 32; o; o >>= 1) m = fmaxf(m, __shfl_xor(m, o));
  if ((t & 63) == 0) mred[t >> 6] = m;
  __syncthreads();
  m = fmaxf(fmaxf(mred[0], mred[1]), fmaxf(mred[2], mred[3]));

  // pass B: slot-strided weighted gather, float4 per lane
  float4 acc = {0.f, 0.f, 0.f, 0.f};
  float wpriv = 0.f;
  for (int i = slot; i < deg; i += 8) {
    float w = __expf(esort[start + i] - m);
    int s = ssort[start + i];
    float4 hv = ((const float4*)(h + (size_t)s * D))[qc];
    acc.x = fmaf(w, hv.x, acc.x);
    acc.y = fmaf(w, hv.y, acc.y);
    acc.z = fmaf(w, hv.z, acc.z);
    acc.w = fmaf(w, hv.w, acc.w);
    wpriv += w;
  }
  part[slot][qc] = acc;
  if (qc == 0) dpart[slot] = wpriv;
  __syncthreads();
  if (slot == 0) {
    float4 s4 = part[0][qc];
#pragma unroll
    for (int s2 = 1; s2 < 8; ++s2) {
      float4 p4 = part[s2][qc];
      s4.x += p4.x; s4.y += p4.y; s4.z += p4.z; s4.w += p4.w;
    }
    float denom = ((dpart[0] + dpart[1]) + (dpart[2] + dpart[3])) +
                  ((dpart[4] + dpart[5]) + (dpart[6] + dpart[7]));
    float inv = 1.f / denom;
    float4 sv = ((const float4*)(sl + (size_t)n * D))[qc];
    float4 r;
    r.x = fmaf(s4.x, inv, sv.x);
    r.y = fmaf(s4.y, inv, sv.y);
    r.z = fmaf(s4.z, inv, sv.z);
    r.w = fmaf(s4.w, inv, sv.w);
    ((float4*)(out + (size_t)n * D))[qc] = r;
  }
}

extern "C" void kernel_launch(void* const* d_in, const int* in_sizes, int n_in,
                              void* d_out, int out_size, void* d_ws, size_t ws_size,
                              hipStream_t stream) {
  const float* h   = (const float*)d_in[0];
  const float* emb = (const float*)d_in[1];
  const float* lw  = (const float*)d_in[2];
  const float* afw = (const float*)d_in[3];
  const float* af2 = (const float*)d_in[4];
  const int* src = (const int*)d_in[5];
  const int* dst = (const int*)d_in[6];
  const int* et  = (const int*)d_in[7];
  int N = in_sizes[0] / D;
  int R = in_sizes[1] / D;
  int E = in_sizes[5];
  float* out = (float*)d_out;

  char* ws = (char*)d_ws;
  size_t o = 0;
  auto alloc = [&](size_t bytes) -> void* {
    void* pp = ws + o;
    o = (o + bytes + 255) & ~(size_t)255;
    return pp;
  };
  float* p     = (float*)alloc((size_t)TD * 4);
  float* ss    = (float*)alloc((size_t)N * 4);
  float* sd    = (float*)alloc((size_t)N * 4);
  float* srel  = (float*)alloc((size_t)R * 4);
  int*   cnt   = (int*)  alloc((size_t)(N + 1) * 4);
  int*   cur   = (int*)  alloc((size_t)N * 4);
  int*   bsum  = (int*)  alloc((size_t)64 * 4);
  float* esort = (float*)alloc((size_t)E * 4);
  int*   ssort = (int*)  alloc((size_t)E * 4);
  float* slws  = (float*)alloc((size_t)N * D * 4);

  int nsb = (N + 1023) / 1024;          // 49 for N=50000 (<= 64 for scan2 wave)

  hipMemsetAsync(cnt, 0, (size_t)(N + 1) * 4, stream);
  k_prep<<<1, TD, 0, stream>>>(afw, af2, p);
  k_sl<<<1024, 256, 0, stream>>>(h, lw, slws, N);
  int nbScore = (N + R + 3) / 4;
  int nbHist = 2048;
  k_scores_hist<<<nbScore + nbHist, 256, 0, stream>>>(h, emb, p, dst, ss, sd, srel,
                                                      cnt, N, R, E, nbScore);
  k_scan1<<<nsb, 1024, 0, stream>>>(cnt, bsum, N);
  k_scan2<<<1, 64, 0, stream>>>(bsum, nsb);
  k_scan3<<<nsb, 1024, 0, stream>>>(bsum, cnt, cur, N, E);
  k_edge<<<(E + 255) / 256, 256, 0, stream>>>(src, dst, et, ss, sd, srel, cur,
                                              esort, ssort, E);
  k_agg<<<N, 256, 0, stream>>>(h, cnt, esort, ssort, slws, out, N);
}

// Round 14
// 333.539 us; speedup vs baseline: 1.1332x; 1.1332x over previous
//
#include <hip/hip_runtime.h>

#define D 128
#define TD 384  // 3*D
#define TN 64   // nodes per block tile in k_sl
#define U  8    // nodes per thread in k_sl

// -------- K_prep: p[t] = sum_i v[i] * A[i*384 + t]  (ps|pd|pr concatenated) ----
__global__ void k_prep(const float* __restrict__ A, const float* __restrict__ v,
                       float* __restrict__ p) {
  __shared__ float vs[D];
  int t = threadIdx.x;
  if (t < D) vs[t] = v[t];
  __syncthreads();
  float acc = 0.f;
#pragma unroll 8
  for (int i = 0; i < D; ++i) acc += vs[i] * A[i * TD + t];
  p[t] = acc;
}

// -------- K_sl: sl = h @ loop_weight. W in LDS (64KB), register-quad reuse:
// thread = (qc: column quad, slot: node group of U=8). Per k-quad the thread
// reads 4 W-quads from LDS ONCE and applies them to 8 nodes (128 FMAs) ->
// 32x fewer LDS ops per FMA than the round-1 version (1 ds_read_b32/FMA,
// 117us). Rounds 3/4/10 proved the allocator refuses to keep 64-128 W floats
// in VGPRs (VGPR_Count 52-72, reload-bound 82-122us), so W must live in LDS.
__global__ __launch_bounds__(256) void k_sl(const float* __restrict__ h,
                                            const float* __restrict__ lw,
                                            float* __restrict__ sl, int N) {
  __shared__ float W[D * D];  // 64KB, W[k][j] row-major
  int t = threadIdx.x;
  for (int i = t; i < D * D / 4; i += 256)
    ((float4*)W)[i] = ((const float4*)lw)[i];
  __syncthreads();
  int qc = t & 31;     // column quad: cols 4*qc..4*qc+3
  int slot = t >> 5;   // node group 0..7
  int ntiles = (N + TN - 1) / TN;
  for (int tile = blockIdx.x; tile < ntiles; tile += gridDim.x) {
    int base = tile * TN + slot * U;
    float4 acc[U];
#pragma unroll
    for (int u = 0; u < U; ++u) acc[u] = make_float4(0.f, 0.f, 0.f, 0.f);
    if ((tile + 1) * TN <= N) {  // full tile: no bounds checks
      for (int k4 = 0; k4 < D / 4; ++k4) {
        int k = k4 * 4;
        float4 w0 = ((const float4*)(W + (size_t)(k + 0) * D))[qc];
        float4 w1 = ((const float4*)(W + (size_t)(k + 1) * D))[qc];
        float4 w2 = ((const float4*)(W + (size_t)(k + 2) * D))[qc];
        float4 w3 = ((const float4*)(W + (size_t)(k + 3) * D))[qc];
#pragma unroll
        for (int u = 0; u < U; ++u) {
          float4 hv = *(const float4*)(h + (size_t)(base + u) * D + k);
          acc[u].x = fmaf(hv.x, w0.x, fmaf(hv.y, w1.x, fmaf(hv.z, w2.x, fmaf(hv.w, w3.x, acc[u].x))));
          acc[u].y = fmaf(hv.x, w0.y, fmaf(hv.y, w1.y, fmaf(hv.z, w2.y, fmaf(hv.w, w3.y, acc[u].y))));
          acc[u].z = fmaf(hv.x, w0.z, fmaf(hv.y, w1.z, fmaf(hv.z, w2.z, fmaf(hv.w, w3.z, acc[u].z))));
          acc[u].w = fmaf(hv.x, w0.w, fmaf(hv.y, w1.w, fmaf(hv.z, w2.w, fmaf(hv.w, w3.w, acc[u].w))));
        }
      }
#pragma unroll
      for (int u = 0; u < U; ++u)
        ((float4*)(sl + (size_t)(base + u) * D))[qc] = acc[u];
    } else {                      // edge tile
      for (int k4 = 0; k4 < D / 4; ++k4) {
        int k = k4 * 4;
        float4 w0 = ((const float4*)(W + (size_t)(k + 0) * D))[qc];
        float4 w1 = ((const float4*)(W + (size_t)(k + 1) * D))[qc];
        float4 w2 = ((const float4*)(W + (size_t)(k + 2) * D))[qc];
        float4 w3 = ((const float4*)(W + (size_t)(k + 3) * D))[qc];
#pragma unroll
        for (int u = 0; u < U; ++u) {
          if (base + u < N) {
            float4 hv = *(const float4*)(h + (size_t)(base + u) * D + k);
            acc[u].x = fmaf(hv.x, w0.x, fmaf(hv.y, w1.x, fmaf(hv.z, w2.x, fmaf(hv.w, w3.x, acc[u].x))));
            acc[u].y = fmaf(hv.x, w0.y, fmaf(hv.y, w1.y, fmaf(hv.z, w2.y, fmaf(hv.w, w3.y, acc[u].y))));
            acc[u].z = fmaf(hv.x, w0.z, fmaf(hv.y, w1.z, fmaf(hv.z, w2.z, fmaf(hv.w, w3.z, acc[u].z))));
            acc[u].w = fmaf(hv.x, w0.w, fmaf(hv.y, w1.w, fmaf(hv.z, w2.w, fmaf(hv.w, w3.w, acc[u].w))));
          }
        }
      }
#pragma unroll
      for (int u = 0; u < U; ++u)
        if (base + u < N)
          ((float4*)(sl + (size_t)(base + u) * D))[qc] = acc[u];
    }
  }
}

// -------- K_scores + histogram (fused): wave-per-node dot products; extra blocks
// do the dst histogram for the CSR build. ------------------------------------
__global__ void k_scores_hist(const float* __restrict__ h, const float* __restrict__ emb,
                              const float* __restrict__ p, const int* __restrict__ dst,
                              float* __restrict__ ss, float* __restrict__ sd,
                              float* __restrict__ sr, int* __restrict__ cnt,
                              int N, int R, int E, int nbScore) {
  int t = threadIdx.x;
  if ((int)blockIdx.x < nbScore) {
    __shared__ float pl[TD];
    pl[t] = p[t];
    if (t < TD - 256) pl[256 + t] = p[256 + t];
    __syncthreads();
    int w = blockIdx.x * 4 + (t >> 6);
    int l = t & 63;
    if (w < N) {
      float x0 = h[(size_t)w * D + l];
      float x1 = h[(size_t)w * D + 64 + l];
      float a = x0 * pl[l] + x1 * pl[64 + l];
      float b = x0 * pl[128 + l] + x1 * pl[192 + l];
#pragma unroll
      for (int o = 32; o; o >>= 1) { a += __shfl_xor(a, o); b += __shfl_xor(b, o); }
      if (l == 0) { ss[w] = a; sd[w] = b; }
    } else if (w < N + R) {
      int r = w - N;
      float x0 = emb[(size_t)r * D + l];
      float x1 = emb[(size_t)r * D + 64 + l];
      float c = x0 * pl[256 + l] + x1 * pl[320 + l];
#pragma unroll
      for (int o = 32; o; o >>= 1) c += __shfl_xor(c, o);
      if (l == 0) sr[r] = c;
    }
  } else {
    int i = (blockIdx.x - nbScore) * 256 + t;
    int stride = (gridDim.x - nbScore) * 256;
    for (; i < E; i += stride) atomicAdd(&cnt[dst[i]], 1);
  }
}

// -------- 3-phase exclusive scan of cnt[0..N-1] ------------------------------
__global__ void k_scan1(int* __restrict__ cnt, int* __restrict__ bsum, int N) {
  __shared__ int wsum[16];
  int t = threadIdx.x, lane = t & 63, wid = t >> 6;
  int i = blockIdx.x * 1024 + t;
  int v = (i < N) ? cnt[i] : 0;
  int x = v;
#pragma unroll
  for (int o = 1; o < 64; o <<= 1) {
    int y = __shfl_up(x, o);
    if (lane >= o) x += y;
  }
  if (lane == 63) wsum[wid] = x;
  __syncthreads();
  if (t < 16) {
    int y = wsum[t];
#pragma unroll
    for (int o = 1; o < 16; o <<= 1) {
      int z = __shfl_up(y, o);
      if (t >= o) y += z;
    }
    wsum[t] = y;
  }
  __syncthreads();
  int woff = wid ? wsum[wid - 1] : 0;
  if (i < N) cnt[i] = woff + x - v;     // block-local exclusive scan
  if (t == 0) bsum[blockIdx.x] = wsum[15];
}

__global__ void k_scan2(int* __restrict__ bsum, int nsb) {
  int l = threadIdx.x;
  int v = (l < nsb) ? bsum[l] : 0;
  int x = v;
#pragma unroll
  for (int o = 1; o < 64; o <<= 1) {
    int y = __shfl_up(x, o);
    if (l >= o) x += y;
  }
  if (l < nsb) bsum[l] = x - v;          // exclusive block offsets, in place
}

__global__ void k_scan3(const int* __restrict__ bsum, int* __restrict__ cnt,
                        int* __restrict__ cur, int N, int E) {
  int i = blockIdx.x * 1024 + threadIdx.x;
  if (i < N) {
    int v = cnt[i] + bsum[blockIdx.x];
    cnt[i] = v;
    cur[i] = v;
  }
  if (i == 0) cnt[N] = E;
}

// -------- K_edge: per-edge logit + scatter into dst-sorted order --------------
__global__ void k_edge(const int* __restrict__ src, const int* __restrict__ dst,
                       const int* __restrict__ et, const float* __restrict__ ss,
                       const float* __restrict__ sd, const float* __restrict__ sr,
                       int* __restrict__ cur, float* __restrict__ esort,
                       int* __restrict__ ssort, int E) {
  int i = blockIdx.x * blockDim.x + threadIdx.x;
  if (i >= E) return;
  int s = src[i], d = dst[i], r = et[i];
  float e = ss[s] + sd[d] + sr[r];
  e = (e > 0.f) ? e : 0.01f * e;
  int pos = atomicAdd(&cur[d], 1);
  esort[pos] = e;
  ssort[pos] = s;
}

// -------- K_agg: one 256-thread block per dst node; fuses the final
// out = agg + sl add (sl = h@W selfloop, computed earlier by k_sl). ----------
__global__ __launch_bounds__(256) void k_agg(const float* __restrict__ h,
                                             const int* __restrict__ off,
                                             const float* __restrict__ esort,
                                             const int* __restrict__ ssort,
                                             const float* __restrict__ sl,
                                             float* __restrict__ out, int N) {
  int n = blockIdx.x;
  int t = threadIdx.x;
  int start = off[n], deg = off[n + 1] - start;
  int qc = t & 31;        // column quad
  int slot = t >> 5;      // edge slot 0..7
  if (deg == 0) {         // DGL keeps h unchanged; plus selfloop term
    if (slot == 0) {
      float4 hv = ((const float4*)(h + (size_t)n * D))[qc];
      float4 sv = ((const float4*)(sl + (size_t)n * D))[qc];
      hv.x += sv.x; hv.y += sv.y; hv.z += sv.z; hv.w += sv.w;
      ((float4*)(out + (size_t)n * D))[qc] = hv;
    }
    return;
  }
  __shared__ float4 part[8][32];
  __shared__ float dpart[8];
  __shared__ float mred[4];

  // pass A: segment max (all 256 threads)
  float m = -3.4e38f;
  for (int i = t; i < deg; i += 256) m = fmaxf(m, esort[start + i]);
#pragma unroll
  for (int o = 32; o; o >>= 1) m = fmaxf(m, __shfl_xor(m, o));
  if ((t & 63) == 0) mred[t >> 6] = m;
  __syncthreads();
  m = fmaxf(fmaxf(mred[0], mred[1]), fmaxf(mred[2], mred[3]));

  // pass B: slot-strided weighted gather, float4 per lane
  float4 acc = {0.f, 0.f, 0.f, 0.f};
  float wpriv = 0.f;
  for (int i = slot; i < deg; i += 8) {
    float w = __expf(esort[start + i] - m);
    int s = ssort[start + i];
    float4 hv = ((const float4*)(h + (size_t)s * D))[qc];
    acc.x = fmaf(w, hv.x, acc.x);
    acc.y = fmaf(w, hv.y, acc.y);
    acc.z = fmaf(w, hv.z, acc.z);
    acc.w = fmaf(w, hv.w, acc.w);
    wpriv += w;
  }
  part[slot][qc] = acc;
  if (qc == 0) dpart[slot] = wpriv;
  __syncthreads();
  if (slot == 0) {
    float4 s4 = part[0][qc];
#pragma unroll
    for (int s2 = 1; s2 < 8; ++s2) {
      float4 p4 = part[s2][qc];
      s4.x += p4.x; s4.y += p4.y; s4.z += p4.z; s4.w += p4.w;
    }
    float denom = ((dpart[0] + dpart[1]) + (dpart[2] + dpart[3])) +
                  ((dpart[4] + dpart[5]) + (dpart[6] + dpart[7]));
    float inv = 1.f / denom;
    float4 sv = ((const float4*)(sl + (size_t)n * D))[qc];
    float4 r;
    r.x = fmaf(s4.x, inv, sv.x);
    r.y = fmaf(s4.y, inv, sv.y);
    r.z = fmaf(s4.z, inv, sv.z);
    r.w = fmaf(s4.w, inv, sv.w);
    ((float4*)(out + (size_t)n * D))[qc] = r;
  }
}

extern "C" void kernel_launch(void* const* d_in, const int* in_sizes, int n_in,
                              void* d_out, int out_size, void* d_ws, size_t ws_size,
                              hipStream_t stream) {
  const float* h   = (const float*)d_in[0];
  const float* emb = (const float*)d_in[1];
  const float* lw  = (const float*)d_in[2];
  const float* afw = (const float*)d_in[3];
  const float* af2 = (const float*)d_in[4];
  const int* src = (const int*)d_in[5];
  const int* dst = (const int*)d_in[6];
  const int* et  = (const int*)d_in[7];
  int N = in_sizes[0] / D;
  int R = in_sizes[1] / D;
  int E = in_sizes[5];
  float* out = (float*)d_out;

  char* ws = (char*)d_ws;
  size_t o = 0;
  auto alloc = [&](size_t bytes) -> void* {
    void* pp = ws + o;
    o = (o + bytes + 255) & ~(size_t)255;
    return pp;
  };
  float* p     = (float*)alloc((size_t)TD * 4);
  float* ss    = (float*)alloc((size_t)N * 4);
  float* sd    = (float*)alloc((size_t)N * 4);
  float* srel  = (float*)alloc((size_t)R * 4);
  int*   cnt   = (int*)  alloc((size_t)(N + 1) * 4);
  int*   cur   = (int*)  alloc((size_t)N * 4);
  int*   bsum  = (int*)  alloc((size_t)64 * 4);
  float* esort = (float*)alloc((size_t)E * 4);
  int*   ssort = (int*)  alloc((size_t)E * 4);
  float* slws  = (float*)alloc((size_t)N * D * 4);

  int nsb = (N + 1023) / 1024;          // 49 for N=50000 (<= 64 for scan2 wave)
  int ntiles = (N + TN - 1) / TN;       // 782 for N=50000

  hipMemsetAsync(cnt, 0, (size_t)(N + 1) * 4, stream);
  k_prep<<<1, TD, 0, stream>>>(afw, af2, p);
  k_sl<<<ntiles, 256, 0, stream>>>(h, lw, slws, N);
  int nbScore = (N + R + 3) / 4;
  int nbHist = 2048;
  k_scores_hist<<<nbScore + nbHist, 256, 0, stream>>>(h, emb, p, dst, ss, sd, srel,
                                                      cnt, N, R, E, nbScore);
  k_scan1<<<nsb, 1024, 0, stream>>>(cnt, bsum, N);
  k_scan2<<<1, 64, 0, stream>>>(bsum, nsb);
  k_scan3<<<nsb, 1024, 0, stream>>>(bsum, cnt, cur, N, E);
  k_edge<<<(E + 255) / 256, 256, 0, stream>>>(src, dst, et, ss, sd, srel, cur,
                                              esort, ssort, E);
  k_agg<<<N, 256, 0, stream>>>(h, cnt, esort, ssort, slws, out, N);
}

// Round 15
// 313.155 us; speedup vs baseline: 1.2069x; 1.0651x over previous
//
#include <hip/hip_runtime.h>

#define D 128
#define TD 384  // 3*D
#define TN 64   // nodes per block tile in k_sl
#define U  8    // nodes per thread in k_sl

// -------- K_prep: p[t] = sum_i v[i] * A[i*384 + t]  (ps|pd|pr concatenated) ----
__global__ void k_prep(const float* __restrict__ A, const float* __restrict__ v,
                       float* __restrict__ p) {
  __shared__ float vs[D];
  int t = threadIdx.x;
  if (t < D) vs[t] = v[t];
  __syncthreads();
  float acc = 0.f;
#pragma unroll 8
  for (int i = 0; i < D; ++i) acc += vs[i] * A[i * TD + t];
  p[t] = acc;
}

// -------- K_sl: sl = h @ loop_weight. W in LDS (64KB), register-quad reuse. ---
__global__ __launch_bounds__(256) void k_sl(const float* __restrict__ h,
                                            const float* __restrict__ lw,
                                            float* __restrict__ sl, int N) {
  __shared__ float W[D * D];  // 64KB, W[k][j] row-major
  int t = threadIdx.x;
  for (int i = t; i < D * D / 4; i += 256)
    ((float4*)W)[i] = ((const float4*)lw)[i];
  __syncthreads();
  int qc = t & 31;     // column quad: cols 4*qc..4*qc+3
  int slot = t >> 5;   // node group 0..7
  int ntiles = (N + TN - 1) / TN;
  for (int tile = blockIdx.x; tile < ntiles; tile += gridDim.x) {
    int base = tile * TN + slot * U;
    float4 acc[U];
#pragma unroll
    for (int u = 0; u < U; ++u) acc[u] = make_float4(0.f, 0.f, 0.f, 0.f);
    if ((tile + 1) * TN <= N) {  // full tile: no bounds checks
      for (int k4 = 0; k4 < D / 4; ++k4) {
        int k = k4 * 4;
        float4 w0 = ((const float4*)(W + (size_t)(k + 0) * D))[qc];
        float4 w1 = ((const float4*)(W + (size_t)(k + 1) * D))[qc];
        float4 w2 = ((const float4*)(W + (size_t)(k + 2) * D))[qc];
        float4 w3 = ((const float4*)(W + (size_t)(k + 3) * D))[qc];
#pragma unroll
        for (int u = 0; u < U; ++u) {
          float4 hv = *(const float4*)(h + (size_t)(base + u) * D + k);
          acc[u].x = fmaf(hv.x, w0.x, fmaf(hv.y, w1.x, fmaf(hv.z, w2.x, fmaf(hv.w, w3.x, acc[u].x))));
          acc[u].y = fmaf(hv.x, w0.y, fmaf(hv.y, w1.y, fmaf(hv.z, w2.y, fmaf(hv.w, w3.y, acc[u].y))));
          acc[u].z = fmaf(hv.x, w0.z, fmaf(hv.y, w1.z, fmaf(hv.z, w2.z, fmaf(hv.w, w3.z, acc[u].z))));
          acc[u].w = fmaf(hv.x, w0.w, fmaf(hv.y, w1.w, fmaf(hv.z, w2.w, fmaf(hv.w, w3.w, acc[u].w))));
        }
      }
#pragma unroll
      for (int u = 0; u < U; ++u)
        ((float4*)(sl + (size_t)(base + u) * D))[qc] = acc[u];
    } else {                      // edge tile
      for (int k4 = 0; k4 < D / 4; ++k4) {
        int k = k4 * 4;
        float4 w0 = ((const float4*)(W + (size_t)(k + 0) * D))[qc];
        float4 w1 = ((const float4*)(W + (size_t)(k + 1) * D))[qc];
        float4 w2 = ((const float4*)(W + (size_t)(k + 2) * D))[qc];
        float4 w3 = ((const float4*)(W + (size_t)(k + 3) * D))[qc];
#pragma unroll
        for (int u = 0; u < U; ++u) {
          if (base + u < N) {
            float4 hv = *(const float4*)(h + (size_t)(base + u) * D + k);
            acc[u].x = fmaf(hv.x, w0.x, fmaf(hv.y, w1.x, fmaf(hv.z, w2.x, fmaf(hv.w, w3.x, acc[u].x))));
            acc[u].y = fmaf(hv.x, w0.y, fmaf(hv.y, w1.y, fmaf(hv.z, w2.y, fmaf(hv.w, w3.y, acc[u].y))));
            acc[u].z = fmaf(hv.x, w0.z, fmaf(hv.y, w1.z, fmaf(hv.z, w2.z, fmaf(hv.w, w3.z, acc[u].z))));
            acc[u].w = fmaf(hv.x, w0.w, fmaf(hv.y, w1.w, fmaf(hv.z, w2.w, fmaf(hv.w, w3.w, acc[u].w))));
          }
        }
      }
#pragma unroll
      for (int u = 0; u < U; ++u)
        if (base + u < N)
          ((float4*)(sl + (size_t)(base + u) * D))[qc] = acc[u];
    }
  }
}

// -------- K_scores + histogram (fused): wave-per-node dot products; extra blocks
// do the dst histogram for the CSR build. ------------------------------------
__global__ void k_scores_hist(const float* __restrict__ h, const float* __restrict__ emb,
                              const float* __restrict__ p, const int* __restrict__ dst,
                              float* __restrict__ ss, float* __restrict__ sd,
                              float* __restrict__ sr, int* __restrict__ cnt,
                              int N, int R, int E, int nbScore) {
  int t = threadIdx.x;
  if ((int)blockIdx.x < nbScore) {
    __shared__ float pl[TD];
    pl[t] = p[t];
    if (t < TD - 256) pl[256 + t] = p[256 + t];
    __syncthreads();
    int w = blockIdx.x * 4 + (t >> 6);
    int l = t & 63;
    if (w < N) {
      float x0 = h[(size_t)w * D + l];
      float x1 = h[(size_t)w * D + 64 + l];
      float a = x0 * pl[l] + x1 * pl[64 + l];
      float b = x0 * pl[128 + l] + x1 * pl[192 + l];
#pragma unroll
      for (int o = 32; o; o >>= 1) { a += __shfl_xor(a, o); b += __shfl_xor(b, o); }
      if (l == 0) { ss[w] = a; sd[w] = b; }
    } else if (w < N + R) {
      int r = w - N;
      float x0 = emb[(size_t)r * D + l];
      float x1 = emb[(size_t)r * D + 64 + l];
      float c = x0 * pl[256 + l] + x1 * pl[320 + l];
#pragma unroll
      for (int o = 32; o; o >>= 1) c += __shfl_xor(c, o);
      if (l == 0) sr[r] = c;
    }
  } else {
    int i = (blockIdx.x - nbScore) * 256 + t;
    int stride = (gridDim.x - nbScore) * 256;
    for (; i < E; i += stride) atomicAdd(&cnt[dst[i]], 1);
  }
}

// -------- 3-phase exclusive scan of cnt[0..N-1] ------------------------------
__global__ void k_scan1(int* __restrict__ cnt, int* __restrict__ bsum, int N) {
  __shared__ int wsum[16];
  int t = threadIdx.x, lane = t & 63, wid = t >> 6;
  int i = blockIdx.x * 1024 + t;
  int v = (i < N) ? cnt[i] : 0;
  int x = v;
#pragma unroll
  for (int o = 1; o < 64; o <<= 1) {
    int y = __shfl_up(x, o);
    if (lane >= o) x += y;
  }
  if (lane == 63) wsum[wid] = x;
  __syncthreads();
  if (t < 16) {
    int y = wsum[t];
#pragma unroll
    for (int o = 1; o < 16; o <<= 1) {
      int z = __shfl_up(y, o);
      if (t >= o) y += z;
    }
    wsum[t] = y;
  }
  __syncthreads();
  int woff = wid ? wsum[wid - 1] : 0;
  if (i < N) cnt[i] = woff + x - v;     // block-local exclusive scan
  if (t == 0) bsum[blockIdx.x] = wsum[15];
}

__global__ void k_scan2(int* __restrict__ bsum, int nsb) {
  int l = threadIdx.x;
  int v = (l < nsb) ? bsum[l] : 0;
  int x = v;
#pragma unroll
  for (int o = 1; o < 64; o <<= 1) {
    int y = __shfl_up(x, o);
    if (l >= o) x += y;
  }
  if (l < nsb) bsum[l] = x - v;          // exclusive block offsets, in place
}

__global__ void k_scan3(const int* __restrict__ bsum, int* __restrict__ cnt,
                        int* __restrict__ cur, int N, int E) {
  int i = blockIdx.x * 1024 + threadIdx.x;
  if (i < N) {
    int v = cnt[i] + bsum[blockIdx.x];
    cnt[i] = v;
    cur[i] = v;
  }
  if (i == 0) cnt[N] = E;
}

// -------- K_edge: per-edge logit + scatter into dst-sorted order. Packs
// (e, src) into one int2 -> single 8B random store instead of two 4B. --------
__global__ void k_edge(const int* __restrict__ src, const int* __restrict__ dst,
                       const int* __restrict__ et, const float* __restrict__ ss,
                       const float* __restrict__ sd, const float* __restrict__ sr,
                       int* __restrict__ cur, int2* __restrict__ epack, int E) {
  int i = blockIdx.x * blockDim.x + threadIdx.x;
  if (i >= E) return;
  int s = src[i], d = dst[i], r = et[i];
  float e = ss[s] + sd[d] + sr[r];
  e = (e > 0.f) ? e : 0.01f * e;
  int pos = atomicAdd(&cur[d], 1);
  int2 pk;
  pk.x = __float_as_int(e);
  pk.y = s;
  epack[pos] = pk;
}

// -------- K_agg: ONE WAVE per dst node (4 nodes per 256-block). Lane =
// (qc = l&31: column quad, es = l>>5: edge parity). Half-wave reads full 512B
// rows coalesced; per-lane loop strides 2 -> ~deg/2 independent gathers in
// flight (vs 2 in the old block-per-node version whose 3-barrier critical
// path made 50K tiny blocks latency-bound at 83us). Halves combine via
// shfl_xor(32). Zero barriers, zero LDS. Fuses out = agg/denom + sl. --------
__global__ __launch_bounds__(256, 8) void k_agg(const float* __restrict__ h,
                                                const int* __restrict__ off,
                                                const int2* __restrict__ epack,
                                                const float* __restrict__ sl,
                                                float* __restrict__ out, int N) {
  int n = blockIdx.x * 4 + (threadIdx.x >> 6);
  if (n >= N) return;                    // wave-uniform
  int l = threadIdx.x & 63;
  int qc = l & 31;
  int es = l >> 5;
  int start = off[n], deg = off[n + 1] - start;

  if (deg == 0) {                        // DGL keeps h unchanged; + selfloop
    if (es == 0) {
      float4 hv = ((const float4*)(h + (size_t)n * D))[qc];
      float4 sv = ((const float4*)(sl + (size_t)n * D))[qc];
      hv.x += sv.x; hv.y += sv.y; hv.z += sv.z; hv.w += sv.w;
      ((float4*)(out + (size_t)n * D))[qc] = hv;
    }
    return;
  }

  // segment max over deg logits (lane-parallel + 64-lane butterfly)
  float m = -3.4e38f;
  for (int i = l; i < deg; i += 64) m = fmaxf(m, __int_as_float(epack[start + i].x));
#pragma unroll
  for (int o = 32; o; o >>= 1) m = fmaxf(m, __shfl_xor(m, o));

  // weighted gather: es handles edges es, es+2, ... (half-wave per row)
  float4 acc = {0.f, 0.f, 0.f, 0.f};
  float wsum = 0.f;
  for (int i = es; i < deg; i += 2) {
    int2 pk = epack[start + i];
    float w = __expf(__int_as_float(pk.x) - m);
    float4 hv = ((const float4*)(h + (size_t)pk.y * D))[qc];
    acc.x = fmaf(w, hv.x, acc.x);
    acc.y = fmaf(w, hv.y, acc.y);
    acc.z = fmaf(w, hv.z, acc.z);
    acc.w = fmaf(w, hv.w, acc.w);
    wsum += w;
  }
  // combine the two halves (lane l <-> l^32)
  acc.x += __shfl_xor(acc.x, 32);
  acc.y += __shfl_xor(acc.y, 32);
  acc.z += __shfl_xor(acc.z, 32);
  acc.w += __shfl_xor(acc.w, 32);
  wsum  += __shfl_xor(wsum, 32);

  if (es == 0) {
    float inv = 1.f / wsum;
    float4 sv = ((const float4*)(sl + (size_t)n * D))[qc];
    float4 r;
    r.x = fmaf(acc.x, inv, sv.x);
    r.y = fmaf(acc.y, inv, sv.y);
    r.z = fmaf(acc.z, inv, sv.z);
    r.w = fmaf(acc.w, inv, sv.w);
    ((float4*)(out + (size_t)n * D))[qc] = r;
  }
}

extern "C" void kernel_launch(void* const* d_in, const int* in_sizes, int n_in,
                              void* d_out, int out_size, void* d_ws, size_t ws_size,
                              hipStream_t stream) {
  const float* h   = (const float*)d_in[0];
  const float* emb = (const float*)d_in[1];
  const float* lw  = (const float*)d_in[2];
  const float* afw = (const float*)d_in[3];
  const float* af2 = (const float*)d_in[4];
  const int* src = (const int*)d_in[5];
  const int* dst = (const int*)d_in[6];
  const int* et  = (const int*)d_in[7];
  int N = in_sizes[0] / D;
  int R = in_sizes[1] / D;
  int E = in_sizes[5];
  float* out = (float*)d_out;

  char* ws = (char*)d_ws;
  size_t o = 0;
  auto alloc = [&](size_t bytes) -> void* {
    void* pp = ws + o;
    o = (o + bytes + 255) & ~(size_t)255;
    return pp;
  };
  float* p     = (float*)alloc((size_t)TD * 4);
  float* ss    = (float*)alloc((size_t)N * 4);
  float* sd    = (float*)alloc((size_t)N * 4);
  float* srel  = (float*)alloc((size_t)R * 4);
  int*   cnt   = (int*)  alloc((size_t)(N + 1) * 4);
  int*   cur   = (int*)  alloc((size_t)N * 4);
  int*   bsum  = (int*)  alloc((size_t)64 * 4);
  int2*  epack = (int2*) alloc((size_t)E * 8);
  float* slws  = (float*)alloc((size_t)N * D * 4);

  int nsb = (N + 1023) / 1024;          // 49 for N=50000 (<= 64 for scan2 wave)
  int ntiles = (N + TN - 1) / TN;       // 782 for N=50000

  hipMemsetAsync(cnt, 0, (size_t)(N + 1) * 4, stream);
  k_prep<<<1, TD, 0, stream>>>(afw, af2, p);
  k_sl<<<ntiles, 256, 0, stream>>>(h, lw, slws, N);
  int nbScore = (N + R + 3) / 4;
  int nbHist = 2048;
  k_scores_hist<<<nbScore + nbHist, 256, 0, stream>>>(h, emb, p, dst, ss, sd, srel,
                                                      cnt, N, R, E, nbScore);
  k_scan1<<<nsb, 1024, 0, stream>>>(cnt, bsum, N);
  k_scan2<<<1, 64, 0, stream>>>(bsum, nsb);
  k_scan3<<<nsb, 1024, 0, stream>>>(bsum, cnt, cur, N, E);
  k_edge<<<(E + 255) / 256, 256, 0, stream>>>(src, dst, et, ss, sd, srel, cur,
                                              epack, E);
  k_agg<<<(N + 3) / 4, 256, 0, stream>>>(h, cnt, epack, slws, out, N);
}